// Round 1
// baseline (97.800 us; speedup 1.0000x reference)
//
#include <hip/hip_runtime.h>

// IDCT: out[b, c, hb*8+p, wb*8+q] = sum_{i,j} H[i*8+p] * x[bc*64 + i*8+j, hb, wb] * H[j*8+q]
// x:   [16, 192, 128, 128] fp32  (bc = b*3+c in [0,48), channel = bc*64 + i*8 + j)
// out: [16, 3, 1024, 1024] fp32
//
// One thread per 8x8 block. Consecutive lanes = consecutive wb -> all 64
// channel-plane loads coalesced (4B/lane). Output rows: 8 contiguous floats
// per thread -> 2x float4 stores.

#define PLANE 16384   // Hb*Wb = 128*128
#define NBLOCKS_TOTAL (48 * 128 * 128)  // bc * hb * wb = 786432

__global__ __launch_bounds__(256) void idct_kernel(const float* __restrict__ x,
                                                   const float* __restrict__ Hm,
                                                   float* __restrict__ out) {
    __shared__ float Hs[64];
    if (threadIdx.x < 64) Hs[threadIdx.x] = Hm[threadIdx.x];
    __syncthreads();

    int tid = blockIdx.x * 256 + threadIdx.x;
    int wb = tid & 127;          // 0..127
    int hb = (tid >> 7) & 127;   // 0..127
    int bc = tid >> 14;          // 0..47

    const float* src = x + (size_t)bc * 64 * PLANE + hb * 128 + wb;

    // Stage 1: tmp[p][j] = sum_i H[i][p] * v[i][j]
    float tmp[8][8];
#pragma unroll
    for (int p = 0; p < 8; ++p)
#pragma unroll
        for (int j = 0; j < 8; ++j) tmp[p][j] = 0.0f;

#pragma unroll
    for (int i = 0; i < 8; ++i) {
        float v[8];
#pragma unroll
        for (int j = 0; j < 8; ++j) v[j] = src[(size_t)(i * 8 + j) * PLANE];
#pragma unroll
        for (int p = 0; p < 8; ++p) {
            float h = Hs[i * 8 + p];
#pragma unroll
            for (int j = 0; j < 8; ++j) tmp[p][j] = fmaf(h, v[j], tmp[p][j]);
        }
    }

    // Stage 2: out[p][q] = sum_j tmp[p][j] * H[j][q], write row-by-row
    float* dst = out + (size_t)bc * (1024u * 1024u) + (size_t)(hb * 8) * 1024 + wb * 8;
#pragma unroll
    for (int p = 0; p < 8; ++p) {
        float o[8];
#pragma unroll
        for (int q = 0; q < 8; ++q) o[q] = 0.0f;
#pragma unroll
        for (int j = 0; j < 8; ++j) {
            float t = tmp[p][j];
#pragma unroll
            for (int q = 0; q < 8; ++q) o[q] = fmaf(t, Hs[j * 8 + q], o[q]);
        }
        float4* d = (float4*)(dst + (size_t)p * 1024);
        d[0] = make_float4(o[0], o[1], o[2], o[3]);
        d[1] = make_float4(o[4], o[5], o[6], o[7]);
    }
}

extern "C" void kernel_launch(void* const* d_in, const int* in_sizes, int n_in,
                              void* d_out, int out_size, void* d_ws, size_t ws_size,
                              hipStream_t stream) {
    const float* x = (const float*)d_in[0];
    const float* H = (const float*)d_in[1];
    float* out = (float*)d_out;

    int threads = 256;
    int blocks = NBLOCKS_TOTAL / threads;  // 3072
    idct_kernel<<<blocks, threads, 0, stream>>>(x, H, out);
}